// Round 4
// baseline (495.136 us; speedup 1.0000x reference)
//
#include <hip/hip_runtime.h>
#include <cstdint>

#define N_NODES 50000
#define N_EDGES 1600000

#define SLICES 8
#define CHUNKS 256
#define EPC (N_EDGES / CHUNKS)        // 6250 edges per chunk
#define NPS (N_NODES / SLICES)        // 6250 nodes per slice

__device__ __forceinline__ unsigned xcc_id() {
    unsigned x;
    asm volatile("s_getreg_b32 %0, hwreg(HW_REG_XCC_ID)" : "=s"(x));
    return x & (SLICES - 1);
}

// L2-local atomic add (workgroup scope -> no device-coherence bit -> executes in local XCD L2).
// Correct only because every atomic to a given line is issued from the owning XCD (enforced
// via xcc_id()-based slicing below).
__device__ __forceinline__ unsigned l2_atomic_inc(unsigned* p) {
    return __hip_atomic_fetch_add(p, 1u, __ATOMIC_RELAXED, __HIP_MEMORY_SCOPE_WORKGROUP);
}

// ---------------- degree counting: XCD-owned slices, L2-local atomics ----------------
__global__ void gcn_count_kernel(const int* __restrict__ src, const int* __restrict__ dst,
                                 unsigned int* __restrict__ outdeg, unsigned int* __restrict__ indeg,
                                 unsigned int* __restrict__ ticket) {
    __shared__ unsigned s_t;
    unsigned slice = xcc_id();
    int lo = slice * NPS, hi = lo + NPS;
    for (;;) {
        if (threadIdx.x == 0) s_t = atomicAdd(&ticket[slice], 1u);  // device-scope, rare
        __syncthreads();
        unsigned t = s_t;
        __syncthreads();
        if (t >= CHUNKS) break;
        int base = t * EPC;
        for (int i = threadIdx.x; i < EPC; i += 256) {
            int s = src[base + i];
            int d = dst[base + i];
            if (s >= lo && s < hi) l2_atomic_inc(&outdeg[s]);
            if (d >= lo && d < hi) l2_atomic_inc(&indeg[d]);
        }
    }
}

// ---------------- exclusive scan ----------------
__global__ void gcn_scan1_kernel(const unsigned int* __restrict__ in, unsigned int* __restrict__ out,
                                 unsigned int* __restrict__ blk, int n) {
    __shared__ unsigned int s[256];
    int tid = threadIdx.x;
    int i = blockIdx.x * 256 + tid;
    unsigned int v = (i < n) ? in[i] : 0u;
    s[tid] = v;
    __syncthreads();
    for (int off = 1; off < 256; off <<= 1) {
        unsigned int t = (tid >= off) ? s[tid - off] : 0u;
        __syncthreads();
        s[tid] += t;
        __syncthreads();
    }
    if (i < n) out[i] = s[tid] - v;  // exclusive
    if (tid == 255) blk[blockIdx.x] = s[255];
}

__global__ void gcn_scan2_kernel(const unsigned int* __restrict__ blk, unsigned int* __restrict__ blkoff, int nblk) {
    __shared__ unsigned int s[256];
    int tid = threadIdx.x;
    unsigned int v = (tid < nblk) ? blk[tid] : 0u;
    s[tid] = v;
    __syncthreads();
    for (int off = 1; off < 256; off <<= 1) {
        unsigned int t = (tid >= off) ? s[tid - off] : 0u;
        __syncthreads();
        s[tid] += t;
        __syncthreads();
    }
    blkoff[tid] = s[tid] - v;
}

// scan3 + norm fused
__global__ void gcn_scan3_kernel(unsigned int* __restrict__ row_ptr, unsigned int* __restrict__ cursor,
                                 const unsigned int* __restrict__ blkoff,
                                 const unsigned int* __restrict__ outdeg,
                                 const unsigned int* __restrict__ indeg,
                                 float* __restrict__ on, float* __restrict__ inn, int n) {
    int i = blockIdx.x * 256 + threadIdx.x;
    if (i < n) {
        unsigned int r = row_ptr[i] + blkoff[blockIdx.x];
        row_ptr[i] = r;
        cursor[i] = r;
        unsigned int od = outdeg[i]; if (od < 1u) od = 1u;
        unsigned int id = indeg[i];  if (id < 1u) id = 1u;
        on[i]  = rsqrtf((float)od);
        inn[i] = rsqrtf((float)id);
    }
    if (i == 0) row_ptr[n] = N_EDGES;
}

// ---------------- CSR fill: XCD-owned slices, L2-local cursor atomics ----------------
__global__ void gcn_fill_kernel(const int* __restrict__ src, const int* __restrict__ dst,
                                unsigned int* __restrict__ cursor, int* __restrict__ csr_src,
                                unsigned int* __restrict__ ticket) {
    __shared__ unsigned s_t;
    unsigned slice = xcc_id();
    int lo = slice * NPS, hi = lo + NPS;
    for (;;) {
        if (threadIdx.x == 0) s_t = atomicAdd(&ticket[slice], 1u);
        __syncthreads();
        unsigned t = s_t;
        __syncthreads();
        if (t >= CHUNKS) break;
        int base = t * EPC;
        for (int i = threadIdx.x; i < EPC; i += 256) {
            int d = dst[base + i];
            if (d >= lo && d < hi) {
                int s = src[base + i];
                unsigned int pos = l2_atomic_inc(&cursor[d]);
                csr_src[pos] = s;   // slice-contiguous region -> local full-line writebacks
            }
        }
    }
}

// ---------------- GEMM helpers ----------------
#define FMA4(A, S, WV) { (A).x += (S)*(WV).x; (A).y += (S)*(WV).y; (A).z += (S)*(WV).z; (A).w += (S)*(WV).w; }

// GEMM1: h = (x * on[:,None]) @ W1  (50000x128 @ 128x128), j-half per block
__global__ __launch_bounds__(256, 4) void gcn_gemm1_kernel(
        const float* __restrict__ x, const float* __restrict__ on,
        const float* __restrict__ W, float* __restrict__ h) {
    __shared__ float4 Ws[128 * 16];      // 32 KiB: half of W's columns
    int tid = threadIdx.x;
    int tile = blockIdx.x >> 1, half = blockIdx.x & 1;
    for (int i = tid; i < 128 * 16; i += 256) {
        int k = i >> 4, q = i & 15;
        Ws[i] = ((const float4*)W)[k * 32 + half * 16 + q];
    }
    __syncthreads();

    int jg = tid & 15;        // float4 group within the 64-output half
    int ns = tid >> 4;        // 0..15
    int n0 = tile * 64 + ns * 4;

    float sc[4]; bool val[4];
    float4 acc[4];
    #pragma unroll
    for (int i = 0; i < 4; ++i) {
        int n = n0 + i; val[i] = (n < N_NODES);
        sc[i] = val[i] ? on[n] : 0.f;
        acc[i] = float4{0.f, 0.f, 0.f, 0.f};
    }

    const float4* xv4 = (const float4*)x;
    float4 xc[4], wc[4], xn[4], wn[4];
    #pragma unroll
    for (int i = 0; i < 4; ++i)
        xc[i] = val[i] ? xv4[(size_t)(n0 + i) * 32] : float4{0.f, 0.f, 0.f, 0.f};
    #pragma unroll
    for (int t = 0; t < 4; ++t) wc[t] = Ws[t * 16 + jg];

    for (int kc = 0; kc < 32; ++kc) {
        if (kc < 31) {
            #pragma unroll
            for (int i = 0; i < 4; ++i)
                xn[i] = val[i] ? xv4[(size_t)(n0 + i) * 32 + kc + 1] : float4{0.f, 0.f, 0.f, 0.f};
            #pragma unroll
            for (int t = 0; t < 4; ++t) wn[t] = Ws[(kc * 4 + 4 + t) * 16 + jg];
        }
        #pragma unroll
        for (int i = 0; i < 4; ++i) {
            FMA4(acc[i], xc[i].x, wc[0]);
            FMA4(acc[i], xc[i].y, wc[1]);
            FMA4(acc[i], xc[i].z, wc[2]);
            FMA4(acc[i], xc[i].w, wc[3]);
        }
        #pragma unroll
        for (int i = 0; i < 4; ++i) xc[i] = xn[i];
        #pragma unroll
        for (int t = 0; t < 4; ++t) wc[t] = wn[t];
    }
    #pragma unroll
    for (int i = 0; i < 4; ++i) {
        if (val[i]) {
            acc[i].x *= sc[i]; acc[i].y *= sc[i]; acc[i].z *= sc[i]; acc[i].w *= sc[i];
            ((float4*)h)[(size_t)(n0 + i) * 32 + half * 16 + jg] = acc[i];
        }
    }
}

// GEMM2: h2 = (h1 * on[:,None]) @ W2  (50000x128 @ 128x64)
__global__ __launch_bounds__(256, 4) void gcn_gemm2_kernel(
        const float* __restrict__ h1, const float* __restrict__ on,
        const float* __restrict__ W, float* __restrict__ h2) {
    __shared__ float4 Ws[128 * 16];      // 32 KiB: all of W2
    int tid = threadIdx.x;
    int tile = blockIdx.x;
    for (int i = tid; i < 128 * 16; i += 256) Ws[i] = ((const float4*)W)[i];
    __syncthreads();

    int jg = tid & 15;        // float4 group over 64 outputs
    int ns = tid >> 4;        // 0..15
    int n0 = tile * 64 + ns * 4;

    float sc[4]; bool val[4];
    float4 acc[4];
    #pragma unroll
    for (int i = 0; i < 4; ++i) {
        int n = n0 + i; val[i] = (n < N_NODES);
        sc[i] = val[i] ? on[n] : 0.f;
        acc[i] = float4{0.f, 0.f, 0.f, 0.f};
    }

    const float4* xv4 = (const float4*)h1;
    float4 xc[4], wc[4], xn[4], wn[4];
    #pragma unroll
    for (int i = 0; i < 4; ++i)
        xc[i] = val[i] ? xv4[(size_t)(n0 + i) * 32] : float4{0.f, 0.f, 0.f, 0.f};
    #pragma unroll
    for (int t = 0; t < 4; ++t) wc[t] = Ws[t * 16 + jg];

    for (int kc = 0; kc < 32; ++kc) {
        if (kc < 31) {
            #pragma unroll
            for (int i = 0; i < 4; ++i)
                xn[i] = val[i] ? xv4[(size_t)(n0 + i) * 32 + kc + 1] : float4{0.f, 0.f, 0.f, 0.f};
            #pragma unroll
            for (int t = 0; t < 4; ++t) wn[t] = Ws[(kc * 4 + 4 + t) * 16 + jg];
        }
        #pragma unroll
        for (int i = 0; i < 4; ++i) {
            FMA4(acc[i], xc[i].x, wc[0]);
            FMA4(acc[i], xc[i].y, wc[1]);
            FMA4(acc[i], xc[i].z, wc[2]);
            FMA4(acc[i], xc[i].w, wc[3]);
        }
        #pragma unroll
        for (int i = 0; i < 4; ++i) xc[i] = xn[i];
        #pragma unroll
        for (int t = 0; t < 4; ++t) wc[t] = wn[t];
    }
    #pragma unroll
    for (int i = 0; i < 4; ++i) {
        if (val[i]) {
            acc[i].x *= sc[i]; acc[i].y *= sc[i]; acc[i].z *= sc[i]; acc[i].w *= sc[i];
            ((float4*)h2)[(size_t)(n0 + i) * 16 + jg] = acc[i];
        }
    }
}

// ---------------- agg1: h1 = relu(segsum(h[src]) * inn + b1) ----------------
__global__ void gcn_agg1_kernel(const float* __restrict__ h, const int* __restrict__ csr,
                                const unsigned int* __restrict__ row_ptr,
                                const float* __restrict__ inn, const float* __restrict__ b1,
                                float* __restrict__ h1) {
    int n = blockIdx.x;
    int tid = threadIdx.x;  // 128
    unsigned int beg = row_ptr[n], end = row_ptr[n + 1];
    __shared__ int es[128];
    float acc = 0.f;
    for (unsigned int base = beg; base < end; base += 128) {
        unsigned int cnt = end - base; if (cnt > 128u) cnt = 128u;
        if (tid < (int)cnt) es[tid] = csr[base + tid];
        __syncthreads();
        for (unsigned int i = 0; i < cnt; ++i) {
            acc += h[(size_t)es[i] * 128 + tid];
        }
        __syncthreads();
    }
    float v = acc * inn[n] + b1[tid];
    h1[(size_t)n * 128 + tid] = fmaxf(v, 0.f);
}

// ---------------- agg2: out = segsum(h2[src]) * inn + b2 ----------------
__global__ void gcn_agg2_kernel(const float* __restrict__ h2, const int* __restrict__ csr,
                                const unsigned int* __restrict__ row_ptr,
                                const float* __restrict__ inn, const float* __restrict__ b2,
                                float* __restrict__ out) {
    int n = blockIdx.x;
    int tid = threadIdx.x;  // 64
    unsigned int beg = row_ptr[n], end = row_ptr[n + 1];
    __shared__ int es[64];
    float acc = 0.f;
    for (unsigned int base = beg; base < end; base += 64) {
        unsigned int cnt = end - base; if (cnt > 64u) cnt = 64u;
        if (tid < (int)cnt) es[tid] = csr[base + tid];
        __syncthreads();
        for (unsigned int i = 0; i < cnt; ++i) {
            acc += h2[(size_t)es[i] * 64 + tid];
        }
        __syncthreads();
    }
    out[(size_t)n * 64 + tid] = acc * inn[n] + b2[tid];
}

extern "C" void kernel_launch(void* const* d_in, const int* in_sizes, int n_in,
                              void* d_out, int out_size, void* d_ws, size_t ws_size,
                              hipStream_t stream) {
    const float* x  = (const float*)d_in[0];
    const float* W1 = (const float*)d_in[1];
    const float* b1 = (const float*)d_in[2];
    const float* W2 = (const float*)d_in[3];
    const float* b2 = (const float*)d_in[4];
    const int*   src = (const int*)d_in[5];
    const int*   dst = (const int*)d_in[6];
    float* out = (float*)d_out;

    char* ws = (char*)d_ws;
    size_t off = 0;
    auto alloc = [&](size_t bytes) -> void* {
        void* p = ws + off;
        off += (bytes + 255) & ~(size_t)255;
        return p;
    };

    unsigned int* outdeg  = (unsigned int*)alloc((size_t)N_NODES * 4);
    unsigned int* indeg   = (unsigned int*)alloc((size_t)N_NODES * 4);
    float*        on      = (float*)alloc((size_t)N_NODES * 4);
    float*        inn     = (float*)alloc((size_t)N_NODES * 4);
    unsigned int* row_ptr = (unsigned int*)alloc((size_t)(N_NODES + 1) * 4);
    unsigned int* cursor  = (unsigned int*)alloc((size_t)N_NODES * 4);
    unsigned int* blksum  = (unsigned int*)alloc(256 * 4);
    unsigned int* blkoff  = (unsigned int*)alloc(256 * 4);
    unsigned int* ticket  = (unsigned int*)alloc(16 * 4);
    int*          csr     = (int*)alloc((size_t)N_EDGES * 4);
    float*        h       = (float*)alloc((size_t)N_NODES * 128 * 4);   // reused as h2
    float*        h1      = (float*)alloc((size_t)N_NODES * 128 * 4);
    float*        h2      = h;   // h dead after agg1

    int nblk_nodes = (N_NODES + 255) / 256;   // 196

    hipMemsetAsync(outdeg, 0, (size_t)N_NODES * 4, stream);
    hipMemsetAsync(indeg,  0, (size_t)N_NODES * 4, stream);
    hipMemsetAsync(ticket, 0, 16 * 4, stream);

    gcn_count_kernel<<<2048, 256, 0, stream>>>(src, dst, outdeg, indeg, ticket);
    gcn_scan1_kernel<<<nblk_nodes, 256, 0, stream>>>(indeg, row_ptr, blksum, N_NODES);
    gcn_scan2_kernel<<<1, 256, 0, stream>>>(blksum, blkoff, nblk_nodes);
    gcn_scan3_kernel<<<nblk_nodes, 256, 0, stream>>>(row_ptr, cursor, blkoff, outdeg, indeg, on, inn, N_NODES);
    gcn_fill_kernel<<<2048, 256, 0, stream>>>(src, dst, cursor, csr, ticket + 8);

    int ntiles = (N_NODES + 63) / 64;         // 782
    gcn_gemm1_kernel<<<ntiles * 2, 256, 0, stream>>>(x, on, W1, h);
    gcn_agg1_kernel<<<N_NODES, 128, 0, stream>>>(h, csr, row_ptr, inn, b1, h1);
    gcn_gemm2_kernel<<<ntiles, 256, 0, stream>>>(h1, on, W2, h2);
    gcn_agg2_kernel<<<N_NODES, 64, 0, stream>>>(h2, csr, row_ptr, inn, b2, out);
}

// Round 5
// 327.882 us; speedup vs baseline: 1.5101x; 1.5101x over previous
//
#include <hip/hip_runtime.h>
#include <cstdint>

#define N_NODES 50000
#define N_EDGES 1600000

#define NCOARSE 196                   // ceil(50000/256)
#define CBLK 256                      // blocks in coarse pass
#define ECHUNK (N_EDGES / CBLK)       // 6250 edges per block

#define OSL 4                         // outdeg slices
#define ONPS (N_NODES / OSL)          // 12500 nodes per slice
#define OPARTS 32
#define OCHUNK (N_EDGES / OPARTS)     // 50000

// ---- K1: per-block coarse histogram of dst>>8 (LDS atomics only) ----
__global__ void k_hist(const int* __restrict__ dst, unsigned* __restrict__ counts) {
    __shared__ unsigned hist[NCOARSE];
    for (int i = threadIdx.x; i < NCOARSE; i += 256) hist[i] = 0;
    __syncthreads();
    int base = blockIdx.x * ECHUNK;
    for (int i = threadIdx.x; i < ECHUNK; i += 256)
        atomicAdd(&hist[(unsigned)dst[base + i] >> 8], 1u);
    __syncthreads();
    for (int i = threadIdx.x; i < NCOARSE; i += 256)
        counts[blockIdx.x * NCOARSE + i] = hist[i];
}

// ---- K2: scan block-counts within each coarse bucket ----
__global__ void k_scanA(const unsigned* __restrict__ counts, unsigned* __restrict__ woff,
                        unsigned* __restrict__ tot) {
    __shared__ unsigned s[256];
    int c = blockIdx.x, t = threadIdx.x;
    unsigned v = counts[t * NCOARSE + c];
    s[t] = v; __syncthreads();
    for (int o = 1; o < 256; o <<= 1) {
        unsigned u = (t >= o) ? s[t - o] : 0u;
        __syncthreads(); s[t] += u; __syncthreads();
    }
    woff[t * NCOARSE + c] = s[t] - v;
    if (t == 255) tot[c] = s[255];
}

// ---- K3: scan bucket totals -> base[], plus row_ptr tail ----
__global__ void k_scanB(const unsigned* __restrict__ tot, unsigned* __restrict__ base,
                        unsigned* __restrict__ row_ptr) {
    __shared__ unsigned s[256];
    int t = threadIdx.x;
    unsigned v = (t < NCOARSE) ? tot[t] : 0u;
    s[t] = v; __syncthreads();
    for (int o = 1; o < 256; o <<= 1) {
        unsigned u = (t >= o) ? s[t - o] : 0u;
        __syncthreads(); s[t] += u; __syncthreads();
    }
    if (t < NCOARSE) base[t] = s[t] - v;
    if (t == NCOARSE - 1) base[NCOARSE] = s[t];   // == N_EDGES
    if (t == 0) row_ptr[N_NODES] = N_EDGES;
}

// ---- K4: coarse scatter into tmp arrays (LDS cursors, run-coalesced stores) ----
__global__ void k_scat1(const int* __restrict__ src, const int* __restrict__ dst,
                        const unsigned* __restrict__ base, const unsigned* __restrict__ woff,
                        int* __restrict__ tmp_s, int* __restrict__ tmp_d) {
    __shared__ unsigned cur[NCOARSE];
    int b = blockIdx.x, t = threadIdx.x;
    for (int i = t; i < NCOARSE; i += 256) cur[i] = base[i] + woff[b * NCOARSE + i];
    __syncthreads();
    int ebase = b * ECHUNK;
    for (int i = t; i < ECHUNK; i += 256) {
        int d = dst[ebase + i], sv = src[ebase + i];
        unsigned p = atomicAdd(&cur[(unsigned)d >> 8], 1u);
        tmp_d[p] = d; tmp_s[p] = sv;
    }
}

// ---- K5: fine scatter within each coarse bucket; emits row_ptr, inn, csr ----
__global__ void k_scat2(const int* __restrict__ tmp_s, const int* __restrict__ tmp_d,
                        const unsigned* __restrict__ base,
                        unsigned* __restrict__ row_ptr, float* __restrict__ inn,
                        int* __restrict__ csr) {
    __shared__ unsigned hist[256], cur[256], s[256];
    int c = blockIdx.x, t = threadIdx.x;
    unsigned beg = base[c], end = base[c + 1];
    hist[t] = 0;
    __syncthreads();
    for (unsigned i = beg + t; i < end; i += 256)
        atomicAdd(&hist[(unsigned)tmp_d[i] & 255u], 1u);
    __syncthreads();
    unsigned v = hist[t];
    s[t] = v; __syncthreads();
    for (int o = 1; o < 256; o <<= 1) {
        unsigned u = (t >= o) ? s[t - o] : 0u;
        __syncthreads(); s[t] += u; __syncthreads();
    }
    unsigned excl = s[t] - v;
    int node = c * 256 + t;
    if (node < N_NODES) {
        row_ptr[node] = beg + excl;
        inn[node] = rsqrtf((float)(v < 1u ? 1u : v));
    }
    cur[t] = beg + excl;
    __syncthreads();
    for (unsigned i = beg + t; i < end; i += 256) {
        int d = tmp_d[i], sv = tmp_s[i];
        unsigned p = atomicAdd(&cur[(unsigned)d & 255u], 1u);
        csr[p] = sv;
    }
}

// ---- K6: outdeg partial histograms (sliced LDS, non-atomic global stores) ----
__global__ void k_odp(const int* __restrict__ src, unsigned short* __restrict__ partial) {
    __shared__ unsigned h[ONPS];      // 48.8 KiB
    int slice = blockIdx.x & (OSL - 1), part = blockIdx.x >> 2;
    int lo = slice * ONPS;
    for (int i = threadIdx.x; i < ONPS; i += 256) h[i] = 0;
    __syncthreads();
    int ebase = part * OCHUNK;
    for (int i = threadIdx.x; i < OCHUNK; i += 256) {
        int sv = src[ebase + i] - lo;
        if ((unsigned)sv < (unsigned)ONPS) atomicAdd(&h[sv], 1u);
    }
    __syncthreads();
    unsigned short* out = partial + (size_t)(slice * OPARTS + part) * ONPS;
    for (int i = threadIdx.x; i < ONPS; i += 256) out[i] = (unsigned short)h[i];
}

// ---- K7: reduce outdeg partials -> on ----
__global__ void k_on(const unsigned short* __restrict__ partial, float* __restrict__ on) {
    int n = blockIdx.x * 256 + threadIdx.x;
    if (n >= N_NODES) return;
    int slice = n / ONPS, i = n % ONPS;
    const unsigned short* p = partial + (size_t)slice * OPARTS * ONPS + i;
    unsigned sum = 0;
    #pragma unroll
    for (int q = 0; q < OPARTS; ++q) sum += p[(size_t)q * ONPS];
    on[n] = rsqrtf((float)(sum < 1u ? 1u : sum));
}

// ---------------- GEMM helpers ----------------
#define FMA4(A, S, WV) { (A).x += (S)*(WV).x; (A).y += (S)*(WV).y; (A).z += (S)*(WV).z; (A).w += (S)*(WV).w; }

// GEMM1: h = (x * on[:,None]) @ W1  (50000x128 @ 128x128), j-half per block
__global__ __launch_bounds__(256, 4) void gcn_gemm1_kernel(
        const float* __restrict__ x, const float* __restrict__ on,
        const float* __restrict__ W, float* __restrict__ h) {
    __shared__ float4 Ws[128 * 16];      // 32 KiB: half of W's columns
    int tid = threadIdx.x;
    int tile = blockIdx.x >> 1, half = blockIdx.x & 1;
    for (int i = tid; i < 128 * 16; i += 256) {
        int k = i >> 4, q = i & 15;
        Ws[i] = ((const float4*)W)[k * 32 + half * 16 + q];
    }
    __syncthreads();

    int jg = tid & 15;
    int ns = tid >> 4;
    int n0 = tile * 64 + ns * 4;

    float sc[4]; bool val[4];
    float4 acc[4];
    #pragma unroll
    for (int i = 0; i < 4; ++i) {
        int n = n0 + i; val[i] = (n < N_NODES);
        sc[i] = val[i] ? on[n] : 0.f;
        acc[i] = float4{0.f, 0.f, 0.f, 0.f};
    }

    const float4* xv4 = (const float4*)x;
    float4 xc[4], wc[4], xn[4], wn[4];
    #pragma unroll
    for (int i = 0; i < 4; ++i)
        xc[i] = val[i] ? xv4[(size_t)(n0 + i) * 32] : float4{0.f, 0.f, 0.f, 0.f};
    #pragma unroll
    for (int t = 0; t < 4; ++t) wc[t] = Ws[t * 16 + jg];

    for (int kc = 0; kc < 32; ++kc) {
        if (kc < 31) {
            #pragma unroll
            for (int i = 0; i < 4; ++i)
                xn[i] = val[i] ? xv4[(size_t)(n0 + i) * 32 + kc + 1] : float4{0.f, 0.f, 0.f, 0.f};
            #pragma unroll
            for (int t = 0; t < 4; ++t) wn[t] = Ws[(kc * 4 + 4 + t) * 16 + jg];
        }
        #pragma unroll
        for (int i = 0; i < 4; ++i) {
            FMA4(acc[i], xc[i].x, wc[0]);
            FMA4(acc[i], xc[i].y, wc[1]);
            FMA4(acc[i], xc[i].z, wc[2]);
            FMA4(acc[i], xc[i].w, wc[3]);
        }
        #pragma unroll
        for (int i = 0; i < 4; ++i) xc[i] = xn[i];
        #pragma unroll
        for (int t = 0; t < 4; ++t) wc[t] = wn[t];
    }
    #pragma unroll
    for (int i = 0; i < 4; ++i) {
        if (val[i]) {
            acc[i].x *= sc[i]; acc[i].y *= sc[i]; acc[i].z *= sc[i]; acc[i].w *= sc[i];
            ((float4*)h)[(size_t)(n0 + i) * 32 + half * 16 + jg] = acc[i];
        }
    }
}

// GEMM2: h2 = (h1 * on[:,None]) @ W2  (50000x128 @ 128x64)
__global__ __launch_bounds__(256, 4) void gcn_gemm2_kernel(
        const float* __restrict__ h1, const float* __restrict__ on,
        const float* __restrict__ W, float* __restrict__ h2) {
    __shared__ float4 Ws[128 * 16];      // 32 KiB: all of W2
    int tid = threadIdx.x;
    int tile = blockIdx.x;
    for (int i = tid; i < 128 * 16; i += 256) Ws[i] = ((const float4*)W)[i];
    __syncthreads();

    int jg = tid & 15;
    int ns = tid >> 4;
    int n0 = tile * 64 + ns * 4;

    float sc[4]; bool val[4];
    float4 acc[4];
    #pragma unroll
    for (int i = 0; i < 4; ++i) {
        int n = n0 + i; val[i] = (n < N_NODES);
        sc[i] = val[i] ? on[n] : 0.f;
        acc[i] = float4{0.f, 0.f, 0.f, 0.f};
    }

    const float4* xv4 = (const float4*)h1;
    float4 xc[4], wc[4], xn[4], wn[4];
    #pragma unroll
    for (int i = 0; i < 4; ++i)
        xc[i] = val[i] ? xv4[(size_t)(n0 + i) * 32] : float4{0.f, 0.f, 0.f, 0.f};
    #pragma unroll
    for (int t = 0; t < 4; ++t) wc[t] = Ws[t * 16 + jg];

    for (int kc = 0; kc < 32; ++kc) {
        if (kc < 31) {
            #pragma unroll
            for (int i = 0; i < 4; ++i)
                xn[i] = val[i] ? xv4[(size_t)(n0 + i) * 32 + kc + 1] : float4{0.f, 0.f, 0.f, 0.f};
            #pragma unroll
            for (int t = 0; t < 4; ++t) wn[t] = Ws[(kc * 4 + 4 + t) * 16 + jg];
        }
        #pragma unroll
        for (int i = 0; i < 4; ++i) {
            FMA4(acc[i], xc[i].x, wc[0]);
            FMA4(acc[i], xc[i].y, wc[1]);
            FMA4(acc[i], xc[i].z, wc[2]);
            FMA4(acc[i], xc[i].w, wc[3]);
        }
        #pragma unroll
        for (int i = 0; i < 4; ++i) xc[i] = xn[i];
        #pragma unroll
        for (int t = 0; t < 4; ++t) wc[t] = wn[t];
    }
    #pragma unroll
    for (int i = 0; i < 4; ++i) {
        if (val[i]) {
            acc[i].x *= sc[i]; acc[i].y *= sc[i]; acc[i].z *= sc[i]; acc[i].w *= sc[i];
            ((float4*)h2)[(size_t)(n0 + i) * 16 + jg] = acc[i];
        }
    }
}

// ---------------- agg1: h1 = relu(segsum(h[src]) * inn + b1) ----------------
__global__ void gcn_agg1_kernel(const float* __restrict__ h, const int* __restrict__ csr,
                                const unsigned int* __restrict__ row_ptr,
                                const float* __restrict__ inn, const float* __restrict__ b1,
                                float* __restrict__ h1) {
    int n = blockIdx.x;
    int tid = threadIdx.x;  // 128
    unsigned int beg = row_ptr[n], end = row_ptr[n + 1];
    __shared__ int es[128];
    float acc = 0.f;
    for (unsigned int base = beg; base < end; base += 128) {
        unsigned int cnt = end - base; if (cnt > 128u) cnt = 128u;
        if (tid < (int)cnt) es[tid] = csr[base + tid];
        __syncthreads();
        for (unsigned int i = 0; i < cnt; ++i) {
            acc += h[(size_t)es[i] * 128 + tid];
        }
        __syncthreads();
    }
    float v = acc * inn[n] + b1[tid];
    h1[(size_t)n * 128 + tid] = fmaxf(v, 0.f);
}

// ---------------- agg2: out = segsum(h2[src]) * inn + b2 ----------------
__global__ void gcn_agg2_kernel(const float* __restrict__ h2, const int* __restrict__ csr,
                                const unsigned int* __restrict__ row_ptr,
                                const float* __restrict__ inn, const float* __restrict__ b2,
                                float* __restrict__ out) {
    int n = blockIdx.x;
    int tid = threadIdx.x;  // 64
    unsigned int beg = row_ptr[n], end = row_ptr[n + 1];
    __shared__ int es[64];
    float acc = 0.f;
    for (unsigned int base = beg; base < end; base += 64) {
        unsigned int cnt = end - base; if (cnt > 64u) cnt = 64u;
        if (tid < (int)cnt) es[tid] = csr[base + tid];
        __syncthreads();
        for (unsigned int i = 0; i < cnt; ++i) {
            acc += h2[(size_t)es[i] * 64 + tid];
        }
        __syncthreads();
    }
    out[(size_t)n * 64 + tid] = acc * inn[n] + b2[tid];
}

extern "C" void kernel_launch(void* const* d_in, const int* in_sizes, int n_in,
                              void* d_out, int out_size, void* d_ws, size_t ws_size,
                              hipStream_t stream) {
    const float* x  = (const float*)d_in[0];
    const float* W1 = (const float*)d_in[1];
    const float* b1 = (const float*)d_in[2];
    const float* W2 = (const float*)d_in[3];
    const float* b2 = (const float*)d_in[4];
    const int*   src = (const int*)d_in[5];
    const int*   dst = (const int*)d_in[6];
    float* out = (float*)d_out;

    char* ws = (char*)d_ws;
    size_t off = 0;
    auto alloc = [&](size_t bytes) -> void* {
        void* p = ws + off;
        off += (bytes + 255) & ~(size_t)255;
        return p;
    };

    float*        on      = (float*)alloc((size_t)N_NODES * 4);
    float*        inn     = (float*)alloc((size_t)N_NODES * 4);
    unsigned int* row_ptr = (unsigned int*)alloc((size_t)(N_NODES + 1) * 4);
    unsigned int* base    = (unsigned int*)alloc((NCOARSE + 1) * 4);
    unsigned int* tot     = (unsigned int*)alloc(NCOARSE * 4);
    int*          csr     = (int*)alloc((size_t)N_EDGES * 4);
    float*        h       = (float*)alloc((size_t)N_NODES * 128 * 4);   // also tmp_s/tmp_d, later h2
    float*        h1      = (float*)alloc((size_t)N_NODES * 128 * 4);   // also partial/counts/woff

    // aliases into dead regions
    int*            tmp_d   = (int*)h;                                   // 6.4 MB
    int*            tmp_s   = (int*)((char*)h + (size_t)N_EDGES * 4);    // 6.4 MB
    unsigned short* partial = (unsigned short*)h1;                       // 3.2 MB
    unsigned int*   counts  = (unsigned int*)((char*)h1 + (4u << 20));   // 200 KB
    unsigned int*   woff    = (unsigned int*)((char*)h1 + (8u << 20));   // 200 KB
    float*          h2      = h;   // h dead after agg1

    // ---- CSR build via 2-level counting sort (zero global atomics) ----
    k_hist <<<CBLK, 256, 0, stream>>>(dst, counts);
    k_scanA<<<NCOARSE, 256, 0, stream>>>(counts, woff, tot);
    k_scanB<<<1, 256, 0, stream>>>(tot, base, row_ptr);
    k_scat1<<<CBLK, 256, 0, stream>>>(src, dst, base, woff, tmp_s, tmp_d);
    k_scat2<<<NCOARSE, 256, 0, stream>>>(tmp_s, tmp_d, base, row_ptr, inn, csr);

    // ---- outdeg -> on (sliced LDS histograms) ----
    k_odp<<<OSL * OPARTS, 256, 0, stream>>>(src, partial);
    k_on <<<(N_NODES + 255) / 256, 256, 0, stream>>>(partial, on);

    // ---- GCN layers ----
    int ntiles = (N_NODES + 63) / 64;         // 782
    gcn_gemm1_kernel<<<ntiles * 2, 256, 0, stream>>>(x, on, W1, h);
    gcn_agg1_kernel<<<N_NODES, 128, 0, stream>>>(h, csr, row_ptr, inn, b1, h1);
    gcn_gemm2_kernel<<<ntiles, 256, 0, stream>>>(h1, on, W2, h2);
    gcn_agg2_kernel<<<N_NODES, 64, 0, stream>>>(h2, csr, row_ptr, inn, b2, out);
}